// Round 7
// baseline (2508.091 us; speedup 1.0000x reference)
//
#include <hip/hip_runtime.h>

#define Bn 64
#define Tn 1024
#define Cn 256

// lgkm-only workgroup barrier (leaves global ops in flight). Proven correct in R6.
#define FWD_SYNC()                                  \
  do {                                              \
    __builtin_amdgcn_sched_barrier(0);              \
    __builtin_amdgcn_s_waitcnt(0xC07F);             \
    __builtin_amdgcn_s_barrier();                   \
    __builtin_amdgcn_sched_barrier(0);              \
  } while (0)

// ---------------- DPP helpers ----------------
template<int CTRL>
__device__ __forceinline__ float dpp_mov_f(float x) {
  return __int_as_float(__builtin_amdgcn_update_dpp(0, __float_as_int(x), CTRL, 0xF, 0xF, true));
}
template<int CTRL>
__device__ __forceinline__ void max_stage(float& v) {
  const float pv = __int_as_float(__builtin_amdgcn_update_dpp(
      (int)0xFF800000, __float_as_int(v), CTRL, 0xF, 0xF, false));
  v = fmaxf(v, pv);
}

// Fast 64-lane argmax (min index on ties). Matches jnp argmax tie-break.
__device__ __forceinline__ int argmax64_fast(float v, int i) {
  float mv = v;
  max_stage<0x111>(mv);  // row_shr:1
  max_stage<0x112>(mv);  // row_shr:2
  max_stage<0x114>(mv);  // row_shr:4
  max_stage<0x118>(mv);  // row_shr:8
  max_stage<0x142>(mv);  // row_bcast15
  max_stage<0x143>(mv);  // row_bcast31  -> lane 63 has global max
  const float smax = __int_as_float(__builtin_amdgcn_readlane(__float_as_int(mv), 63));
  const unsigned long long m = __ballot(v == smax);
  const int ln = __ffsll((unsigned long long)m) - 1;
  return __builtin_amdgcn_readlane(i, ln);
}

// Padded alpha LDS layout (R3-verified: conflicts 5.0e7 -> 512):
// chunk m at float offset (m>>2)*20 + (m&3)*4. Buffer = 320 floats.
__device__ __forceinline__ int apad(int m) { return (m >> 2) * 20 + (m & 3) * 4; }

// One batch-step: read alpha from LDS, 64 MACs vs tr4, 16-lane rotate-reduce,
// leader adds emission + writes next alpha. Identical arithmetic to R3 (verified).
__device__ __forceinline__ void fwd_step_batch(
    const float* __restrict__ avc, float* __restrict__ aw, int woff,
    const float4* __restrict__ tr4, bool leader,
    float4& e4, float4& pna, float4 pf) {
  float m0 = -__builtin_inff(), m1 = m0, m2 = m0, m3 = m0;
#pragma unroll
  for (int j = 0; j < 4; ++j) {
    const float4 a = *(const float4*)(avc + j * 4);
    float4 t0 = tr4[4 * j + 0];
    m0 = fmaxf(m0, a.x + t0.x); m1 = fmaxf(m1, a.x + t0.y);
    m2 = fmaxf(m2, a.x + t0.z); m3 = fmaxf(m3, a.x + t0.w);
    float4 t1 = tr4[4 * j + 1];
    m0 = fmaxf(m0, a.y + t1.x); m1 = fmaxf(m1, a.y + t1.y);
    m2 = fmaxf(m2, a.y + t1.z); m3 = fmaxf(m3, a.y + t1.w);
    float4 t2 = tr4[4 * j + 2];
    m0 = fmaxf(m0, a.z + t2.x); m1 = fmaxf(m1, a.z + t2.y);
    m2 = fmaxf(m2, a.z + t2.z); m3 = fmaxf(m3, a.z + t2.w);
    float4 t3 = tr4[4 * j + 3];
    m0 = fmaxf(m0, a.w + t3.x); m1 = fmaxf(m1, a.w + t3.y);
    m2 = fmaxf(m2, a.w + t3.z); m3 = fmaxf(m3, a.w + t3.w);
  }
  // rotate-reduce max across the 16 c-lanes of this DPP row (exact)
  m0 = fmaxf(m0, dpp_mov_f<0x128>(m0)); m1 = fmaxf(m1, dpp_mov_f<0x128>(m1));
  m2 = fmaxf(m2, dpp_mov_f<0x128>(m2)); m3 = fmaxf(m3, dpp_mov_f<0x128>(m3));
  m0 = fmaxf(m0, dpp_mov_f<0x124>(m0)); m1 = fmaxf(m1, dpp_mov_f<0x124>(m1));
  m2 = fmaxf(m2, dpp_mov_f<0x124>(m2)); m3 = fmaxf(m3, dpp_mov_f<0x124>(m3));
  m0 = fmaxf(m0, dpp_mov_f<0x122>(m0)); m1 = fmaxf(m1, dpp_mov_f<0x122>(m1));
  m2 = fmaxf(m2, dpp_mov_f<0x122>(m2)); m3 = fmaxf(m3, dpp_mov_f<0x122>(m3));
  m0 = fmaxf(m0, dpp_mov_f<0x121>(m0)); m1 = fmaxf(m1, dpp_mov_f<0x121>(m1));
  m2 = fmaxf(m2, dpp_mov_f<0x121>(m2)); m3 = fmaxf(m3, dpp_mov_f<0x121>(m3));
  if (leader) {
    float4 na;
    na.x = m0 + e4.x; na.y = m1 + e4.y; na.z = m2 + e4.z; na.w = m3 + e4.w;
    *(float4*)(aw + woff) = na;
    pna = na;
    e4 = pf;
  }
}

// ---------------- Kernel A: forward, TWO batches per block ----------------
// R6 found fwd is phase-locked: all waves read LDS (pipe ~960cy, VALU idle),
// then all compute (~630cy, LDS idle) + barrier latency => 2243cy/step.
// Fix: interleave 2 batches per 16-wave block. tr4 depends only on (c,ccb) —
// shared by both batches, so zero extra trans registers. A's reads overlap B's
// compute (independent LDS buffers); barrier paid once per TWO batch-steps.
// Blocks 0..31: batches 2bi, 2bi+1. Blocks 32..47: transpose trans -> transT.
__global__ __launch_bounds__(1024) void crf_fwd_kernel(
    float* __restrict__ seq, const float* __restrict__ trans,
    float* __restrict__ transT, int useT) {
  __shared__ float lds[64 * 65];  // fwd: 4x320 floats; transpose: 64x65
  const int bi = blockIdx.x;
  const int tid = threadIdx.x;

  if (bi < Bn / 2) {
    float* sbA = seq + (size_t)(2 * bi) * (Tn * Cn);
    float* sbB = seq + (size_t)(2 * bi + 1) * (Tn * Cn);
    const int l = tid & 63;
    const int w = tid >> 6;     // wave 0..15
    const int c = l & 15;       // cp-chunk lane (reduction index)
    const int g = l >> 4;       // cc-group within wave
    const int ccb = w * 16 + g * 4;  // 4 consecutive cc
    const int cpb = c * 16;          // 16 consecutive cp
    float4 tr4[16];  // trans[cpb+k][ccb..ccb+3] — shared by both batches
#pragma unroll
    for (int k = 0; k < 16; ++k)
      tr4[k] = *(const float4*)(trans + (size_t)(cpb + k) * Cn + ccb);

    float* abA0 = lds;        float* abA1 = lds + 320;
    float* abB0 = lds + 640;  float* abB1 = lds + 960;
    if (tid < 64) *(float4*)(abA0 + apad(tid)) = ((const float4*)sbA)[tid];
    else if (tid < 128) *(float4*)(abB0 + apad(tid - 64)) = ((const float4*)sbB)[tid - 64];
    const bool leader = (c == 0);
    const int woff = apad(w * 4 + g);
    float4 e4A, pnaA, e4B, pnaB;
    if (leader) {
      e4A = *(const float4*)(sbA + Cn + ccb);
      e4B = *(const float4*)(sbB + Cn + ccb);
    }
    FWD_SYNC();

    for (int t = 1; t < Tn; ++t) {
      float4 pfA, pfB;
      if (leader) {
        if (t > 1) {
          *(float4*)(sbA + (size_t)(t - 1) * Cn + ccb) = pnaA;
          *(float4*)(sbB + (size_t)(t - 1) * Cn + ccb) = pnaB;
        }
        const int tn = (t + 1 < Tn) ? (t + 1) : (Tn - 1);
        pfA = *(const float4*)(sbA + (size_t)tn * Cn + ccb);
        pfB = *(const float4*)(sbB + (size_t)tn * Cn + ccb);
      }
      const int par = t & 1;
      const float* avA = par ? abA0 : abA1;
      float* awA = par ? abA1 : abA0;
      const float* avB = par ? abB0 : abB1;
      float* awB = par ? abB1 : abB0;
      fwd_step_batch(avA + c * 20, awA, woff, tr4, leader, e4A, pnaA, pfA);
      fwd_step_batch(avB + c * 20, awB, woff, tr4, leader, e4B, pnaB, pfB);
      FWD_SYNC();
    }
    if (leader) {
      *(float4*)(sbA + (size_t)(Tn - 1) * Cn + ccb) = pnaA;
      *(float4*)(sbB + (size_t)(Tn - 1) * Cn + ccb) = pnaB;
    }
  } else if (useT) {
    // 64x64-tile transpose of trans into transT, LDS-staged, +1-padded
    const int idx = bi - Bn / 2;  // 0..15
    const int ti = idx >> 2, tj = idx & 3;
    const int tx = tid & 63, ty = tid >> 6;  // ty 0..15
#pragma unroll
    for (int q = 0; q < 4; ++q) {
      const int row = q * 16 + ty;
      lds[tx * 65 + row] = trans[(size_t)(ti * 64 + row) * Cn + tj * 64 + tx];
    }
    __syncthreads();
#pragma unroll
    for (int q = 0; q < 4; ++q) {
      const int row = q * 16 + ty;
      transT[(size_t)(tj * 64 + row) * Cn + ti * 64 + tx] = lds[row * 65 + tx];
    }
  }
}

// ---------------- bwd helpers ----------------
__device__ __forceinline__ float4 onehot4(int tg, int cp0) {
  float4 z;
  z.x = (tg == cp0 + 0) ? 1.0f : 0.0f; z.y = (tg == cp0 + 1) ? 1.0f : 0.0f;
  z.z = (tg == cp0 + 2) ? 1.0f : 0.0f; z.w = (tg == cp0 + 3) ? 1.0f : 0.0f;
  return z;
}

template<int K>
__device__ __forceinline__ int chain_chunk(
    const float* __restrict__ A, int* __restrict__ tags,
    const float* __restrict__ transT, int tag, int l) {
  const int cp0 = l * 4;
#pragma unroll
  for (int k = 0; k < K; ++k) {
    const float4 tv = *(const float4*)(transT + (size_t)tag * Cn + cp0);
    const float4 ac = *(const float4*)(A + k * Cn + cp0);
    float v = ac.x + tv.x; int i = cp0;
    float vv; bool cnd;
    vv = ac.y + tv.y; cnd = vv > v; v = cnd ? vv : v; i = cnd ? cp0 + 1 : i;
    vv = ac.z + tv.z; cnd = vv > v; v = cnd ? vv : v; i = cnd ? cp0 + 2 : i;
    vv = ac.w + tv.w; cnd = vv > v; v = cnd ? vv : v; i = cnd ? cp0 + 3 : i;
    tag = argmax64_fast(v, i);
    if (l == 0) tags[k] = tag;
  }
  return tag;
}

// ---------------- Kernel B: producer-consumer backtrack + one-hot -------------
// (R5 structure, verified ~353us.) Wave0: pure dependent chain. Waves1-2:
// prefetch alpha rows global->LDS ring. Wave3: one-hot stores.
__global__ __launch_bounds__(256) void crf_bwd_kernel(
    const float* __restrict__ seq, const float* __restrict__ trans,
    const float* __restrict__ transT, float* __restrict__ out, int useT) {
  __shared__ float aL[2][16][Cn];   // 32 KB alpha ring
  __shared__ int tagL[2][16];
  const int b = blockIdx.x;
  const int tid = threadIdx.x;
  const int wv = tid >> 6;
  const int l = tid & 63;
  const int cp0 = l * 4;
  const float* sb = seq + (size_t)b * (Tn * Cn);  // alpha trail
  float* ob = out + (size_t)b * (Tn * Cn);

  if (!useT) {
    if (wv == 0) {
      float4 a = *(const float4*)(sb + (size_t)(Tn - 1) * Cn + cp0);
      float v = a.x; int i = cp0; bool cnd;
      cnd = a.y > v; v = cnd ? a.y : v; i = cnd ? cp0 + 1 : i;
      cnd = a.z > v; v = cnd ? a.z : v; i = cnd ? cp0 + 2 : i;
      cnd = a.w > v; v = cnd ? a.w : v; i = cnd ? cp0 + 3 : i;
      int tag = argmax64_fast(v, i);
      *(float4*)(ob + (size_t)(Tn - 1) * Cn + cp0) = onehot4(tag, cp0);
      for (int t = Tn - 2; t >= 0; --t) {
        const float4 ac = *(const float4*)(sb + (size_t)t * Cn + cp0);
        float4 tv;
        tv.x = trans[(size_t)(cp0 + 0) * Cn + tag];
        tv.y = trans[(size_t)(cp0 + 1) * Cn + tag];
        tv.z = trans[(size_t)(cp0 + 2) * Cn + tag];
        tv.w = trans[(size_t)(cp0 + 3) * Cn + tag];
        float v2 = ac.x + tv.x; int i2 = cp0; float vv; bool c2;
        vv = ac.y + tv.y; c2 = vv > v2; v2 = c2 ? vv : v2; i2 = c2 ? cp0 + 1 : i2;
        vv = ac.z + tv.z; c2 = vv > v2; v2 = c2 ? vv : v2; i2 = c2 ? cp0 + 2 : i2;
        vv = ac.w + tv.w; c2 = vv > v2; v2 = c2 ? vv : v2; i2 = c2 ? cp0 + 3 : i2;
        tag = argmax64_fast(v2, i2);
        *(float4*)(ob + (size_t)t * Cn + cp0) = onehot4(tag, cp0);
      }
    }
    return;
  }

  int tag = 0;
  if (wv == 0) {
    float4 a = *(const float4*)(sb + (size_t)(Tn - 1) * Cn + cp0);
    float v = a.x; int i = cp0; bool cnd;
    cnd = a.y > v; v = cnd ? a.y : v; i = cnd ? cp0 + 1 : i;
    cnd = a.z > v; v = cnd ? a.z : v; i = cnd ? cp0 + 2 : i;
    cnd = a.w > v; v = cnd ? a.w : v; i = cnd ? cp0 + 3 : i;
    tag = argmax64_fast(v, i);
    *(float4*)(ob + (size_t)(Tn - 1) * Cn + cp0) = onehot4(tag, cp0);
  } else if (wv <= 2) {
    const int s0 = (wv == 1) ? 0 : 8, s1 = (wv == 1) ? 8 : 15;
    for (int s = s0; s < s1; ++s)
      *(float4*)(&aL[0][s][cp0]) = *(const float4*)(sb + (size_t)(1022 - s) * Cn + cp0);
  }
  __syncthreads();

  int p = 0, t0 = 1022, K = 15, pt0 = 0, pK = 0;
  for (int ch = 0; ch < 64; ++ch) {
    const int nt0 = t0 - K;
    if (wv == 0) {
      if (ch == 0) tag = chain_chunk<15>(&aL[p][0][0], tagL[p], transT, tag, l);
      else        tag = chain_chunk<16>(&aL[p][0][0], tagL[p], transT, tag, l);
    } else if (wv <= 2) {
      if (ch < 63) {
        const int s0 = (wv == 1) ? 0 : 8, s1 = (wv == 1) ? 8 : 16;
        for (int s = s0; s < s1; ++s)
          *(float4*)(&aL[1 - p][s][cp0]) =
              *(const float4*)(sb + (size_t)(nt0 - s) * Cn + cp0);
      }
    } else {
      if (ch > 0) {
        for (int k = 0; k < pK; ++k)
          *(float4*)(ob + (size_t)(pt0 - k) * Cn + cp0) =
              onehot4(tagL[1 - p][k], cp0);
      }
    }
    __syncthreads();
    pt0 = t0; pK = K; t0 = nt0; K = 16; p ^= 1;
  }
  if (wv == 3) {
    for (int k = 0; k < 16; ++k)
      *(float4*)(ob + (size_t)(15 - k) * Cn + cp0) = onehot4(tagL[1][k], cp0);
  }
}

extern "C" void kernel_launch(void* const* d_in, const int* in_sizes, int n_in,
                              void* d_out, int out_size, void* d_ws, size_t ws_size,
                              hipStream_t stream) {
  float* seq = (float*)d_in[0];
  const float* trans = (const float*)d_in[1];
  float* out = (float*)d_out;
  float* transT = (float*)d_ws;
  const int useT = (ws_size >= (size_t)Cn * Cn * sizeof(float)) ? 1 : 0;

  crf_fwd_kernel<<<dim3(Bn / 2 + 16), dim3(1024), 0, stream>>>(seq, trans, transT, useT);
  crf_bwd_kernel<<<dim3(Bn), dim3(256), 0, stream>>>(seq, trans, transT, out, useT);
}

// Round 9
// 1266.100 us; speedup vs baseline: 1.9810x; 1.9810x over previous
//
#include <hip/hip_runtime.h>

#define Bn 64
#define Tn 1024
#define Cn 256

// Native clang vector for nontemporal builtins (HIP's float4 is a class type,
// which __builtin_nontemporal_* rejects). Same 16B layout as float4.
typedef float nv4 __attribute__((ext_vector_type(4)));

__device__ __forceinline__ float4 nt_load4(const float* p) {
  nv4 r = __builtin_nontemporal_load((const nv4*)p);
  return make_float4(r.x, r.y, r.z, r.w);
}
__device__ __forceinline__ void nt_store4(float* p, float4 v) {
  nv4 r = {v.x, v.y, v.z, v.w};
  __builtin_nontemporal_store(r, (nv4*)p);
}

// ---------------- DPP helpers ----------------
template<int CTRL>
__device__ __forceinline__ float dpp_mov_f(float x) {
  return __int_as_float(__builtin_amdgcn_update_dpp(0, __float_as_int(x), CTRL, 0xF, 0xF, true));
}
template<int CTRL>
__device__ __forceinline__ void max_stage(float& v) {
  const float pv = __int_as_float(__builtin_amdgcn_update_dpp(
      (int)0xFF800000, __float_as_int(v), CTRL, 0xF, 0xF, false));
  v = fmaxf(v, pv);
}

// Fast 64-lane argmax (min index on ties). Matches jnp argmax tie-break.
__device__ __forceinline__ int argmax64_fast(float v, int i) {
  float mv = v;
  max_stage<0x111>(mv);  // row_shr:1
  max_stage<0x112>(mv);  // row_shr:2
  max_stage<0x114>(mv);  // row_shr:4
  max_stage<0x118>(mv);  // row_shr:8
  max_stage<0x142>(mv);  // row_bcast15
  max_stage<0x143>(mv);  // row_bcast31  -> lane 63 has global max
  const float smax = __int_as_float(__builtin_amdgcn_readlane(__float_as_int(mv), 63));
  const unsigned long long m = __ballot(v == smax);
  const int ln = __ffsll((unsigned long long)m) - 1;
  return __builtin_amdgcn_readlane(i, ln);
}

// Padded alpha LDS layout (R3-verified: conflicts 5.0e7 -> 512):
// chunk m at float offset (m>>2)*20 + (m&3)*4. Buffer = 320 floats.
__device__ __forceinline__ int apad(int m) { return (m >> 2) * 20 + (m & 3) * 4; }

// ---------------- Kernel A: forward max-plus scan (+ trans transpose) ----------------
// R3-exact structure (best measured fwd: 931us). KEY R8 change:
// __launch_bounds__(1024, 4) -> VGPR budget 128 (implicit default starved tr4
// into AGPRs; every MAC then paid a v_accvgpr_read -> VALU-issue bound;
// VGPR_Count=52 was the smoking gun).
__global__ __launch_bounds__(1024, 4) void crf_fwd_kernel(
    float* __restrict__ seq, const float* __restrict__ trans,
    float* __restrict__ transT, int useT) {
  __shared__ float lds[64 * 65];
  const int bi = blockIdx.x;
  const int tid = threadIdx.x;

  if (bi < Bn) {
    float* sb = seq + (size_t)bi * (Tn * Cn);
    const int l = tid & 63;
    const int w = tid >> 6;     // wave 0..15
    const int c = l & 15;       // cp-chunk within DPP row (reduction index)
    const int g = l >> 4;       // cc-group within wave
    const int ccb = w * 16 + g * 4;  // 4 consecutive cc
    const int cpb = c * 16;          // 16 consecutive cp
    float4 tr4[16];  // trans[cpb+k][ccb..ccb+3] — must live in real VGPRs
#pragma unroll
    for (int k = 0; k < 16; ++k)
      tr4[k] = *(const float4*)(trans + (size_t)(cpb + k) * Cn + ccb);

    float* ab0 = lds;        // 320 floats (padded)
    float* ab1 = lds + 320;
    if (tid < 64) *(float4*)(ab0 + apad(tid)) = ((const float4*)sb)[tid];
    const bool leader = (c == 0);
    const int woff = apad(w * 4 + g);
    float4 e4, pna;
    if (leader) e4 = *(const float4*)(sb + Cn + ccb);  // emissions[1]
    __syncthreads();

    for (int t = 1; t < Tn; ++t) {
      float4 pf;
      if (leader) {
        if (t > 1) *(float4*)(sb + (size_t)(t - 1) * Cn + ccb) = pna;
        const int tn = (t + 1 < Tn) ? (t + 1) : (Tn - 1);
        pf = *(const float4*)(sb + (size_t)tn * Cn + ccb);
      }
      const float* av = (t & 1) ? ab0 : ab1;
      float* aw = (t & 1) ? ab1 : ab0;
      const float* avc = av + c * 20;
      float m0 = -__builtin_inff(), m1 = m0, m2 = m0, m3 = m0;
#pragma unroll
      for (int j = 0; j < 4; ++j) {
        const float4 a = *(const float4*)(avc + j * 4);
        float4 t0 = tr4[4 * j + 0];
        m0 = fmaxf(m0, a.x + t0.x); m1 = fmaxf(m1, a.x + t0.y);
        m2 = fmaxf(m2, a.x + t0.z); m3 = fmaxf(m3, a.x + t0.w);
        float4 t1 = tr4[4 * j + 1];
        m0 = fmaxf(m0, a.y + t1.x); m1 = fmaxf(m1, a.y + t1.y);
        m2 = fmaxf(m2, a.y + t1.z); m3 = fmaxf(m3, a.y + t1.w);
        float4 t2 = tr4[4 * j + 2];
        m0 = fmaxf(m0, a.z + t2.x); m1 = fmaxf(m1, a.z + t2.y);
        m2 = fmaxf(m2, a.z + t2.z); m3 = fmaxf(m3, a.z + t2.w);
        float4 t3 = tr4[4 * j + 3];
        m0 = fmaxf(m0, a.w + t3.x); m1 = fmaxf(m1, a.w + t3.y);
        m2 = fmaxf(m2, a.w + t3.z); m3 = fmaxf(m3, a.w + t3.w);
      }
      // rotate-reduce max across the 16 c-lanes of this DPP row (exact)
      m0 = fmaxf(m0, dpp_mov_f<0x128>(m0)); m1 = fmaxf(m1, dpp_mov_f<0x128>(m1));
      m2 = fmaxf(m2, dpp_mov_f<0x128>(m2)); m3 = fmaxf(m3, dpp_mov_f<0x128>(m3));
      m0 = fmaxf(m0, dpp_mov_f<0x124>(m0)); m1 = fmaxf(m1, dpp_mov_f<0x124>(m1));
      m2 = fmaxf(m2, dpp_mov_f<0x124>(m2)); m3 = fmaxf(m3, dpp_mov_f<0x124>(m3));
      m0 = fmaxf(m0, dpp_mov_f<0x122>(m0)); m1 = fmaxf(m1, dpp_mov_f<0x122>(m1));
      m2 = fmaxf(m2, dpp_mov_f<0x122>(m2)); m3 = fmaxf(m3, dpp_mov_f<0x122>(m3));
      m0 = fmaxf(m0, dpp_mov_f<0x121>(m0)); m1 = fmaxf(m1, dpp_mov_f<0x121>(m1));
      m2 = fmaxf(m2, dpp_mov_f<0x121>(m2)); m3 = fmaxf(m3, dpp_mov_f<0x121>(m3));
      if (leader) {
        float4 na;
        na.x = m0 + e4.x; na.y = m1 + e4.y; na.z = m2 + e4.z; na.w = m3 + e4.w;
        *(float4*)(aw + woff) = na;
        pna = na;
        e4 = pf;
      }
      __syncthreads();
    }
    if (leader) *(float4*)(sb + (size_t)(Tn - 1) * Cn + ccb) = pna;
  } else if (useT) {
    // 64x64-tile transpose of trans into transT, LDS-staged, +1-padded
    const int idx = bi - Bn;  // 0..15
    const int ti = idx >> 2, tj = idx & 3;
    const int tx = tid & 63, ty = tid >> 6;  // ty 0..15
#pragma unroll
    for (int q = 0; q < 4; ++q) {
      const int row = q * 16 + ty;
      lds[tx * 65 + row] = trans[(size_t)(ti * 64 + row) * Cn + tj * 64 + tx];
    }
    __syncthreads();
#pragma unroll
    for (int q = 0; q < 4; ++q) {
      const int row = q * 16 + ty;
      transT[(size_t)(tj * 64 + row) * Cn + ti * 64 + tx] = lds[row * 65 + tx];
    }
  }
}

// ---------------- bwd helpers ----------------
__device__ __forceinline__ float4 onehot4(int tg, int cp0) {
  float4 z;
  z.x = (tg == cp0 + 0) ? 1.0f : 0.0f; z.y = (tg == cp0 + 1) ? 1.0f : 0.0f;
  z.z = (tg == cp0 + 2) ? 1.0f : 0.0f; z.w = (tg == cp0 + 3) ? 1.0f : 0.0f;
  return z;
}

template<int K>
__device__ __forceinline__ int chain_chunk(
    const float* __restrict__ A, int* __restrict__ tags,
    const float* __restrict__ transT, int tag, int l) {
  const int cp0 = l * 4;
#pragma unroll
  for (int k = 0; k < K; ++k) {
    const float4 tv = *(const float4*)(transT + (size_t)tag * Cn + cp0);
    const float4 ac = *(const float4*)(A + k * Cn + cp0);
    float v = ac.x + tv.x; int i = cp0;
    float vv; bool cnd;
    vv = ac.y + tv.y; cnd = vv > v; v = cnd ? vv : v; i = cnd ? cp0 + 1 : i;
    vv = ac.z + tv.z; cnd = vv > v; v = cnd ? vv : v; i = cnd ? cp0 + 2 : i;
    vv = ac.w + tv.w; cnd = vv > v; v = cnd ? vv : v; i = cnd ? cp0 + 3 : i;
    tag = argmax64_fast(v, i);
    if (l == 0) tags[k] = tag;
  }
  return tag;
}

// ---------------- Kernel B: producer-consumer backtrack + one-hot -------------
// (R5 structure, ~353us.) Wave0: pure dependent chain (only vmem = transT[tag]).
// Waves1-2: prefetch alpha rows global->LDS ring — NON-TEMPORAL (R8): the 64MB
// trail was streaming through L2 and evicting transT, turning the chain's row
// loads into ~900cy HBM misses. Wave3: one-hot stores — also non-temporal.
__global__ __launch_bounds__(256) void crf_bwd_kernel(
    const float* __restrict__ seq, const float* __restrict__ trans,
    const float* __restrict__ transT, float* __restrict__ out, int useT) {
  __shared__ float aL[2][16][Cn];   // 32 KB alpha ring
  __shared__ int tagL[2][16];
  const int b = blockIdx.x;
  const int tid = threadIdx.x;
  const int wv = tid >> 6;
  const int l = tid & 63;
  const int cp0 = l * 4;
  const float* sb = seq + (size_t)b * (Tn * Cn);  // alpha trail
  float* ob = out + (size_t)b * (Tn * Cn);

  if (!useT) {
    if (wv == 0) {
      float4 a = *(const float4*)(sb + (size_t)(Tn - 1) * Cn + cp0);
      float v = a.x; int i = cp0; bool cnd;
      cnd = a.y > v; v = cnd ? a.y : v; i = cnd ? cp0 + 1 : i;
      cnd = a.z > v; v = cnd ? a.z : v; i = cnd ? cp0 + 2 : i;
      cnd = a.w > v; v = cnd ? a.w : v; i = cnd ? cp0 + 3 : i;
      int tag = argmax64_fast(v, i);
      *(float4*)(ob + (size_t)(Tn - 1) * Cn + cp0) = onehot4(tag, cp0);
      for (int t = Tn - 2; t >= 0; --t) {
        const float4 ac = *(const float4*)(sb + (size_t)t * Cn + cp0);
        float4 tv;
        tv.x = trans[(size_t)(cp0 + 0) * Cn + tag];
        tv.y = trans[(size_t)(cp0 + 1) * Cn + tag];
        tv.z = trans[(size_t)(cp0 + 2) * Cn + tag];
        tv.w = trans[(size_t)(cp0 + 3) * Cn + tag];
        float v2 = ac.x + tv.x; int i2 = cp0; float vv; bool c2;
        vv = ac.y + tv.y; c2 = vv > v2; v2 = c2 ? vv : v2; i2 = c2 ? cp0 + 1 : i2;
        vv = ac.z + tv.z; c2 = vv > v2; v2 = c2 ? vv : v2; i2 = c2 ? cp0 + 2 : i2;
        vv = ac.w + tv.w; c2 = vv > v2; v2 = c2 ? vv : v2; i2 = c2 ? cp0 + 3 : i2;
        tag = argmax64_fast(v2, i2);
        *(float4*)(ob + (size_t)t * Cn + cp0) = onehot4(tag, cp0);
      }
    }
    return;
  }

  int tag = 0;
  if (wv == 0) {
    float4 a = *(const float4*)(sb + (size_t)(Tn - 1) * Cn + cp0);
    float v = a.x; int i = cp0; bool cnd;
    cnd = a.y > v; v = cnd ? a.y : v; i = cnd ? cp0 + 1 : i;
    cnd = a.z > v; v = cnd ? a.z : v; i = cnd ? cp0 + 2 : i;
    cnd = a.w > v; v = cnd ? a.w : v; i = cnd ? cp0 + 3 : i;
    tag = argmax64_fast(v, i);
    *(float4*)(ob + (size_t)(Tn - 1) * Cn + cp0) = onehot4(tag, cp0);
  } else if (wv <= 2) {
    const int s0 = (wv == 1) ? 0 : 8, s1 = (wv == 1) ? 8 : 15;
    for (int s = s0; s < s1; ++s)
      *(float4*)(&aL[0][s][cp0]) = nt_load4(sb + (size_t)(1022 - s) * Cn + cp0);
  }
  __syncthreads();

  int p = 0, t0 = 1022, K = 15, pt0 = 0, pK = 0;
  for (int ch = 0; ch < 64; ++ch) {
    const int nt0 = t0 - K;
    if (wv == 0) {
      if (ch == 0) tag = chain_chunk<15>(&aL[p][0][0], tagL[p], transT, tag, l);
      else        tag = chain_chunk<16>(&aL[p][0][0], tagL[p], transT, tag, l);
    } else if (wv <= 2) {
      if (ch < 63) {
        const int s0 = (wv == 1) ? 0 : 8, s1 = (wv == 1) ? 8 : 16;
        for (int s = s0; s < s1; ++s)
          *(float4*)(&aL[1 - p][s][cp0]) = nt_load4(sb + (size_t)(nt0 - s) * Cn + cp0);
      }
    } else {
      if (ch > 0) {
        for (int k = 0; k < pK; ++k)
          nt_store4(ob + (size_t)(pt0 - k) * Cn + cp0, onehot4(tagL[1 - p][k], cp0));
      }
    }
    __syncthreads();
    pt0 = t0; pK = K; t0 = nt0; K = 16; p ^= 1;
  }
  if (wv == 3) {
    for (int k = 0; k < 16; ++k)
      nt_store4(ob + (size_t)(15 - k) * Cn + cp0, onehot4(tagL[1][k], cp0));
  }
}

extern "C" void kernel_launch(void* const* d_in, const int* in_sizes, int n_in,
                              void* d_out, int out_size, void* d_ws, size_t ws_size,
                              hipStream_t stream) {
  float* seq = (float*)d_in[0];
  const float* trans = (const float*)d_in[1];
  float* out = (float*)d_out;
  float* transT = (float*)d_ws;
  const int useT = (ws_size >= (size_t)Cn * Cn * sizeof(float)) ? 1 : 0;

  crf_fwd_kernel<<<dim3(Bn + 16), dim3(1024), 0, stream>>>(seq, trans, transT, useT);
  crf_bwd_kernel<<<dim3(Bn), dim3(256), 0, stream>>>(seq, trans, transT, out, useT);
}

// Round 10
// 1260.998 us; speedup vs baseline: 1.9890x; 1.0040x over previous
//
#include <hip/hip_runtime.h>

#define Bn 64
#define Tn 1024
#define Cn 256
#define TCROWS 127  // transT rows cached in bwd LDS (127KB + 32KB ring + tags < 160KB)

// Native clang vector for nontemporal builtins (HIP float4 is a class type).
typedef float nv4 __attribute__((ext_vector_type(4)));
__device__ __forceinline__ float4 nt_load4(const float* p) {
  nv4 r = __builtin_nontemporal_load((const nv4*)p);
  return make_float4(r.x, r.y, r.z, r.w);
}
__device__ __forceinline__ void nt_store4(float* p, float4 v) {
  nv4 r = {v.x, v.y, v.z, v.w};
  __builtin_nontemporal_store(r, (nv4*)p);
}

// ---------------- DPP helpers ----------------
template<int CTRL>
__device__ __forceinline__ float dpp_mov_f(float x) {
  return __int_as_float(__builtin_amdgcn_update_dpp(0, __float_as_int(x), CTRL, 0xF, 0xF, true));
}
template<int CTRL>
__device__ __forceinline__ void max_stage(float& v) {
  const float pv = __int_as_float(__builtin_amdgcn_update_dpp(
      (int)0xFF800000, __float_as_int(v), CTRL, 0xF, 0xF, false));
  v = fmaxf(v, pv);
}

// Fast 64-lane argmax (min index on ties). Matches jnp argmax tie-break.
__device__ __forceinline__ int argmax64_fast(float v, int i) {
  float mv = v;
  max_stage<0x111>(mv);  // row_shr:1
  max_stage<0x112>(mv);  // row_shr:2
  max_stage<0x114>(mv);  // row_shr:4
  max_stage<0x118>(mv);  // row_shr:8
  max_stage<0x142>(mv);  // row_bcast15
  max_stage<0x143>(mv);  // row_bcast31  -> lane 63 has global max
  const float smax = __int_as_float(__builtin_amdgcn_readlane(__float_as_int(mv), 63));
  const unsigned long long m = __ballot(v == smax);
  const int ln = __ffsll((unsigned long long)m) - 1;
  return __builtin_amdgcn_readlane(i, ln);
}

// Padded alpha LDS layout (R3-verified: conflicts 5.0e7 -> 512):
// chunk m at float offset (m>>2)*20 + (m&3)*4. Buffer = 320 floats.
__device__ __forceinline__ int apad(int m) { return (m >> 2) * 20 + (m & 3) * 4; }

// One 4cp x 4cc MAC block: acc = max(acc, a.{xyzw} + tr4[4j+q].{xyzw})
#define MAC4(a_, jj, M0, M1, M2, M3)                                          \
  {                                                                           \
    const float4 t0 = tr4[4 * (jj) + 0];                                      \
    M0 = fmaxf(M0, (a_).x + t0.x); M1 = fmaxf(M1, (a_).x + t0.y);             \
    M2 = fmaxf(M2, (a_).x + t0.z); M3 = fmaxf(M3, (a_).x + t0.w);             \
    const float4 t1 = tr4[4 * (jj) + 1];                                      \
    M0 = fmaxf(M0, (a_).y + t1.x); M1 = fmaxf(M1, (a_).y + t1.y);             \
    M2 = fmaxf(M2, (a_).y + t1.z); M3 = fmaxf(M3, (a_).y + t1.w);             \
    const float4 t2 = tr4[4 * (jj) + 2];                                      \
    M0 = fmaxf(M0, (a_).z + t2.x); M1 = fmaxf(M1, (a_).z + t2.y);             \
    M2 = fmaxf(M2, (a_).z + t2.z); M3 = fmaxf(M3, (a_).z + t2.w);             \
    const float4 t3 = tr4[4 * (jj) + 3];                                      \
    M0 = fmaxf(M0, (a_).w + t3.x); M1 = fmaxf(M1, (a_).w + t3.y);             \
    M2 = fmaxf(M2, (a_).w + t3.z); M3 = fmaxf(M3, (a_).w + t3.w);             \
  }

// ---------------- Kernel A: forward max-plus scan (+ trans transpose) ----------------
// R3 structure. R10: alpha LDS reads issued FIRST in the loop body; each
// accumulator's fmax chain split into two independent 8-deep halves (exact —
// max is associative) to shorten the per-step serial tail.
__global__ __launch_bounds__(1024, 4) void crf_fwd_kernel(
    float* __restrict__ seq, const float* __restrict__ trans,
    float* __restrict__ transT, int useT) {
  __shared__ float lds[64 * 65];
  const int bi = blockIdx.x;
  const int tid = threadIdx.x;

  if (bi < Bn) {
    float* sb = seq + (size_t)bi * (Tn * Cn);
    const int l = tid & 63;
    const int w = tid >> 6;     // wave 0..15
    const int c = l & 15;       // cp-chunk lane (reduction index)
    const int g = l >> 4;       // cc-group within wave
    const int ccb = w * 16 + g * 4;  // 4 consecutive cc
    const int cpb = c * 16;          // 16 consecutive cp
    float4 tr4[16];  // trans fragment (unified-file AGPR residency is free)
#pragma unroll
    for (int k = 0; k < 16; ++k)
      tr4[k] = *(const float4*)(trans + (size_t)(cpb + k) * Cn + ccb);

    float* ab0 = lds;        // 320 floats (padded)
    float* ab1 = lds + 320;
    if (tid < 64) *(float4*)(ab0 + apad(tid)) = ((const float4*)sb)[tid];
    const bool leader = (c == 0);
    const int woff = apad(w * 4 + g);
    float4 e4, pna;
    if (leader) e4 = *(const float4*)(sb + Cn + ccb);  // emissions[1]
    __syncthreads();

    for (int t = 1; t < Tn; ++t) {
      // 1) issue this step's alpha LDS reads immediately after the barrier
      const float* av = (t & 1) ? ab0 : ab1;
      float* aw = (t & 1) ? ab1 : ab0;
      const float* avc = av + c * 20;
      const float4 a0 = *(const float4*)(avc + 0);
      const float4 a1 = *(const float4*)(avc + 4);
      const float4 a2 = *(const float4*)(avc + 8);
      const float4 a3 = *(const float4*)(avc + 12);
      // 2) leader global traffic overlaps the LDS latency
      float4 pf;
      if (leader) {
        if (t > 1) *(float4*)(sb + (size_t)(t - 1) * Cn + ccb) = pna;
        const int tn = (t + 1 < Tn) ? (t + 1) : (Tn - 1);
        pf = *(const float4*)(sb + (size_t)tn * Cn + ccb);
      }
      // 3) MACs: two independent 8-deep chains per accumulator, then combine
      const float ninf = -__builtin_inff();
      float p0 = ninf, p1 = ninf, p2 = ninf, p3 = ninf;
      float q0 = ninf, q1 = ninf, q2 = ninf, q3 = ninf;
      MAC4(a0, 0, p0, p1, p2, p3)
      MAC4(a2, 2, q0, q1, q2, q3)
      MAC4(a1, 1, p0, p1, p2, p3)
      MAC4(a3, 3, q0, q1, q2, q3)
      float m0 = fmaxf(p0, q0), m1 = fmaxf(p1, q1);
      float m2 = fmaxf(p2, q2), m3 = fmaxf(p3, q3);
      // rotate-reduce max across the 16 c-lanes of this DPP row (exact)
      m0 = fmaxf(m0, dpp_mov_f<0x128>(m0)); m1 = fmaxf(m1, dpp_mov_f<0x128>(m1));
      m2 = fmaxf(m2, dpp_mov_f<0x128>(m2)); m3 = fmaxf(m3, dpp_mov_f<0x128>(m3));
      m0 = fmaxf(m0, dpp_mov_f<0x124>(m0)); m1 = fmaxf(m1, dpp_mov_f<0x124>(m1));
      m2 = fmaxf(m2, dpp_mov_f<0x124>(m2)); m3 = fmaxf(m3, dpp_mov_f<0x124>(m3));
      m0 = fmaxf(m0, dpp_mov_f<0x122>(m0)); m1 = fmaxf(m1, dpp_mov_f<0x122>(m1));
      m2 = fmaxf(m2, dpp_mov_f<0x122>(m2)); m3 = fmaxf(m3, dpp_mov_f<0x122>(m3));
      m0 = fmaxf(m0, dpp_mov_f<0x121>(m0)); m1 = fmaxf(m1, dpp_mov_f<0x121>(m1));
      m2 = fmaxf(m2, dpp_mov_f<0x121>(m2)); m3 = fmaxf(m3, dpp_mov_f<0x121>(m3));
      if (leader) {
        float4 na;
        na.x = m0 + e4.x; na.y = m1 + e4.y; na.z = m2 + e4.z; na.w = m3 + e4.w;
        *(float4*)(aw + woff) = na;
        pna = na;
        e4 = pf;
      }
      __syncthreads();
    }
    if (leader) *(float4*)(sb + (size_t)(Tn - 1) * Cn + ccb) = pna;
  } else if (useT) {
    // 64x64-tile transpose of trans into transT, LDS-staged, +1-padded
    const int idx = bi - Bn;  // 0..15
    const int ti = idx >> 2, tj = idx & 3;
    const int tx = tid & 63, ty = tid >> 6;  // ty 0..15
#pragma unroll
    for (int q = 0; q < 4; ++q) {
      const int row = q * 16 + ty;
      lds[tx * 65 + row] = trans[(size_t)(ti * 64 + row) * Cn + tj * 64 + tx];
    }
    __syncthreads();
#pragma unroll
    for (int q = 0; q < 4; ++q) {
      const int row = q * 16 + ty;
      transT[(size_t)(tj * 64 + row) * Cn + ti * 64 + tx] = lds[row * 65 + tx];
    }
  }
}

// ---------------- bwd helpers ----------------
__device__ __forceinline__ float4 onehot4(int tg, int cp0) {
  float4 z;
  z.x = (tg == cp0 + 0) ? 1.0f : 0.0f; z.y = (tg == cp0 + 1) ? 1.0f : 0.0f;
  z.z = (tg == cp0 + 2) ? 1.0f : 0.0f; z.w = (tg == cp0 + 3) ? 1.0f : 0.0f;
  return z;
}

// Chain chunk: per step, the dependent row load hits the LDS transT cache for
// tag < TCROWS (~40cy) else L2 (~200cy). tag is SGPR-uniform -> scalar branch.
template<int K>
__device__ __forceinline__ int chain_chunk(
    const float* __restrict__ A, int* __restrict__ tags,
    const float* __restrict__ transT, const float* __restrict__ tc,
    int tag, int l) {
  const int cp0 = l * 4;
#pragma unroll
  for (int k = 0; k < K; ++k) {
    float4 tv;
    if (tag < TCROWS) {
      tv = *(const float4*)(tc + tag * Cn + cp0);
    } else {
      tv = *(const float4*)(transT + (size_t)tag * Cn + cp0);
    }
    const float4 ac = *(const float4*)(A + k * Cn + cp0);
    float v = ac.x + tv.x; int i = cp0;
    float vv; bool cnd;
    vv = ac.y + tv.y; cnd = vv > v; v = cnd ? vv : v; i = cnd ? cp0 + 1 : i;
    vv = ac.z + tv.z; cnd = vv > v; v = cnd ? vv : v; i = cnd ? cp0 + 2 : i;
    vv = ac.w + tv.w; cnd = vv > v; v = cnd ? vv : v; i = cnd ? cp0 + 3 : i;
    tag = argmax64_fast(v, i);
    if (l == 0) tags[k] = tag;
  }
  return tag;
}

// ---------------- Kernel B: producer-consumer backtrack + one-hot -------------
// Wave0: dependent chain. Waves1-2: alpha global->LDS ring (non-temporal).
// Wave3: one-hot stores (non-temporal). R10: 127 transT rows cached in LDS.
__global__ __launch_bounds__(256) void crf_bwd_kernel(
    const float* __restrict__ seq, const float* __restrict__ trans,
    const float* __restrict__ transT, float* __restrict__ out, int useT) {
  __shared__ float aL[2][16][Cn];     // 32 KB alpha ring
  __shared__ float tc[TCROWS * Cn];   // 127 KB transT row cache
  __shared__ int tagL[2][16];
  const int b = blockIdx.x;
  const int tid = threadIdx.x;
  const int wv = tid >> 6;
  const int l = tid & 63;
  const int cp0 = l * 4;
  const float* sb = seq + (size_t)b * (Tn * Cn);  // alpha trail
  float* ob = out + (size_t)b * (Tn * Cn);

  if (!useT) {
    if (wv == 0) {
      float4 a = *(const float4*)(sb + (size_t)(Tn - 1) * Cn + cp0);
      float v = a.x; int i = cp0; bool cnd;
      cnd = a.y > v; v = cnd ? a.y : v; i = cnd ? cp0 + 1 : i;
      cnd = a.z > v; v = cnd ? a.z : v; i = cnd ? cp0 + 2 : i;
      cnd = a.w > v; v = cnd ? a.w : v; i = cnd ? cp0 + 3 : i;
      int tag = argmax64_fast(v, i);
      *(float4*)(ob + (size_t)(Tn - 1) * Cn + cp0) = onehot4(tag, cp0);
      for (int t = Tn - 2; t >= 0; --t) {
        const float4 ac = *(const float4*)(sb + (size_t)t * Cn + cp0);
        float4 tv;
        tv.x = trans[(size_t)(cp0 + 0) * Cn + tag];
        tv.y = trans[(size_t)(cp0 + 1) * Cn + tag];
        tv.z = trans[(size_t)(cp0 + 2) * Cn + tag];
        tv.w = trans[(size_t)(cp0 + 3) * Cn + tag];
        float v2 = ac.x + tv.x; int i2 = cp0; float vv; bool c2;
        vv = ac.y + tv.y; c2 = vv > v2; v2 = c2 ? vv : v2; i2 = c2 ? cp0 + 1 : i2;
        vv = ac.z + tv.z; c2 = vv > v2; v2 = c2 ? vv : v2; i2 = c2 ? cp0 + 2 : i2;
        vv = ac.w + tv.w; c2 = vv > v2; v2 = c2 ? vv : v2; i2 = c2 ? cp0 + 3 : i2;
        tag = argmax64_fast(v2, i2);
        *(float4*)(ob + (size_t)t * Cn + cp0) = onehot4(tag, cp0);
      }
    }
    return;
  }

  // Preload the transT LDS cache: wave wv loads rows [32*wv, min(127, 32*wv+32))
  {
    const int r0 = wv * 32;
    const int r1 = (r0 + 32 < TCROWS) ? (r0 + 32) : TCROWS;
    for (int r = r0; r < r1; ++r)
      *(float4*)(&tc[r * Cn + cp0]) = *(const float4*)(transT + (size_t)r * Cn + cp0);
  }

  int tag = 0;
  if (wv == 0) {
    float4 a = *(const float4*)(sb + (size_t)(Tn - 1) * Cn + cp0);
    float v = a.x; int i = cp0; bool cnd;
    cnd = a.y > v; v = cnd ? a.y : v; i = cnd ? cp0 + 1 : i;
    cnd = a.z > v; v = cnd ? a.z : v; i = cnd ? cp0 + 2 : i;
    cnd = a.w > v; v = cnd ? a.w : v; i = cnd ? cp0 + 3 : i;
    tag = argmax64_fast(v, i);
    *(float4*)(ob + (size_t)(Tn - 1) * Cn + cp0) = onehot4(tag, cp0);
  } else if (wv <= 2) {
    const int s0 = (wv == 1) ? 0 : 8, s1 = (wv == 1) ? 8 : 15;
    for (int s = s0; s < s1; ++s)
      *(float4*)(&aL[0][s][cp0]) = nt_load4(sb + (size_t)(1022 - s) * Cn + cp0);
  }
  __syncthreads();

  int p = 0, t0 = 1022, K = 15, pt0 = 0, pK = 0;
  for (int ch = 0; ch < 64; ++ch) {
    const int nt0 = t0 - K;
    if (wv == 0) {
      if (ch == 0) tag = chain_chunk<15>(&aL[p][0][0], tagL[p], transT, tc, tag, l);
      else        tag = chain_chunk<16>(&aL[p][0][0], tagL[p], transT, tc, tag, l);
    } else if (wv <= 2) {
      if (ch < 63) {
        const int s0 = (wv == 1) ? 0 : 8, s1 = (wv == 1) ? 8 : 16;
        for (int s = s0; s < s1; ++s)
          *(float4*)(&aL[1 - p][s][cp0]) = nt_load4(sb + (size_t)(nt0 - s) * Cn + cp0);
      }
    } else {
      if (ch > 0) {
        for (int k = 0; k < pK; ++k)
          nt_store4(ob + (size_t)(pt0 - k) * Cn + cp0, onehot4(tagL[1 - p][k], cp0));
      }
    }
    __syncthreads();
    pt0 = t0; pK = K; t0 = nt0; K = 16; p ^= 1;
  }
  if (wv == 3) {
    for (int k = 0; k < 16; ++k)
      nt_store4(ob + (size_t)(15 - k) * Cn + cp0, onehot4(tagL[1][k], cp0));
  }
}

extern "C" void kernel_launch(void* const* d_in, const int* in_sizes, int n_in,
                              void* d_out, int out_size, void* d_ws, size_t ws_size,
                              hipStream_t stream) {
  float* seq = (float*)d_in[0];
  const float* trans = (const float*)d_in[1];
  float* out = (float*)d_out;
  float* transT = (float*)d_ws;
  const int useT = (ws_size >= (size_t)Cn * Cn * sizeof(float)) ? 1 : 0;

  crf_fwd_kernel<<<dim3(Bn + 16), dim3(1024), 0, stream>>>(seq, trans, transT, useT);
  crf_bwd_kernel<<<dim3(Bn), dim3(256), 0, stream>>>(seq, trans, transT, out, useT);
}